// Round 1
// 1437.363 us; speedup vs baseline: 1.0636x; 1.0636x over previous
//
#include <hip/hip_runtime.h>
#include <stdint.h>

// ============================================================================
// GRU_Model: 2-layer bidirectional GRU, B=512 T=64 E=300 H=512, fp16 MFMA.
//
// Round-2 change (scan kernel only):
//  - group barrier: per-producer flag vector (relaxed sc1 stores) instead of
//    a single fetch-add counter -> no 16-deep serialized RMW chain at MALL.
//  - every wave polls the 16 flags itself (coalesced 64B load + __all) and
//    proceeds without a trailing __syncthreads.
//  - gx loads for step s+1 are issued after the flag store, hiding their
//    L3/HBM latency behind the barrier wait.
// ============================================================================

#define NTW 192   // 3072/16 gate-column tiles (both dirs)
#define MTX 2048  // 32768/16 row tiles (B*T)

typedef _Float16 half8 __attribute__((ext_vector_type(8)));
typedef _Float16 half4_t __attribute__((ext_vector_type(4)));
typedef float float4_t __attribute__((ext_vector_type(4)));

__device__ __forceinline__ void gl_lds16(const void* g, void* l) {
  __builtin_amdgcn_global_load_lds(
      (const __attribute__((address_space(1))) void*)g,
      (__attribute__((address_space(3))) void*)l, 16, 0, 0);
}

__device__ __forceinline__ float sigm_f(float x) { return 1.f / (1.f + __expf(-x)); }
__device__ __forceinline__ float tanh_f(float x) { return 1.f - 2.f / (__expf(2.f * x) + 1.f); }

// f32 (3072, K) row-major -> fp16 frag layout [192][KI][64][8], zero-pad to KI*32
__global__ void pack_b_kernel(const float* __restrict__ src, _Float16* __restrict__ dst,
                              int K, int KI) {
  int gid = blockIdx.x * 256 + threadIdx.x;
  int l = gid & 63, unit = gid >> 6;
  int nt = unit / KI, ks = unit - nt * KI;
  if (nt >= NTW) return;
  int row = nt * 16 + (l & 15);
  int col0 = ks * 32 + ((l >> 4) << 3);
  half8 v;
#pragma unroll
  for (int j = 0; j < 8; ++j) {
    int c = col0 + j;
    v[j] = (c < K) ? (_Float16)src[(long)row * K + c] : (_Float16)0.f;
  }
  *(half8*)(dst + (long)unit * 512 + l * 8) = v;
}

// embedding gather -> x0 frag layout [2048][10][64][8] (K=300 padded to 320)
__global__ void gather_kernel(const int* __restrict__ tokens, const float* __restrict__ emb,
                              _Float16* __restrict__ x0) {
  int gid = blockIdx.x * 256 + threadIdx.x;
  int l = gid & 63, unit = gid >> 6;
  int mt = unit / 10, ks = unit - mt * 10;
  if (mt >= MTX) return;
  int row = mt * 16 + (l & 15);  // row = b*64 + t
  const float* e = emb + (long)tokens[row] * 300;
  int col0 = ks * 32 + ((l >> 4) << 3);
  half8 v;
#pragma unroll
  for (int j = 0; j < 8; ++j) {
    int c = col0 + j;
    v[j] = (c < 300) ? (_Float16)e[c] : (_Float16)0.f;
  }
  *(half8*)(x0 + (long)unit * 512 + l * 8) = v;
}

// C(M=32768,N=3072) = A(M,K) * B(N,K)^T + bias[n];  A,B frag-layout fp16,
// C in C-frag tile layout [mtile][ntile][256] fp16.  grid (24, 256), 256 thr.
__global__ __launch_bounds__(256) void gemm_bt_kernel(
    const _Float16* __restrict__ A, const _Float16* __restrict__ Bw,
    const float* __restrict__ bias, _Float16* __restrict__ C, int KI) {
  __shared__ _Float16 As[8 * 512];
  __shared__ _Float16 Bs[8 * 512];
  const int bx = blockIdx.x, by = blockIdx.y;
  const int tid = threadIdx.x, w = tid >> 6, l = tid & 63;
  const int wm = w >> 1, wn = w & 1, ln = l & 15;
  const int mt0 = by * 8, nt0 = bx * 8;
  float4_t acc[4][4];
#pragma unroll
  for (int i = 0; i < 4; ++i)
#pragma unroll
    for (int j = 0; j < 4; ++j) acc[i][j] = 0.f;
  for (int it = 0; it < KI; ++it) {
    __syncthreads();  // protect LDS from previous iter's readers
    gl_lds16(A + ((long)(mt0 + w) * KI + it) * 512 + l * 8, As + w * 512 + l * 8);
    gl_lds16(A + ((long)(mt0 + w + 4) * KI + it) * 512 + l * 8, As + (w + 4) * 512 + l * 8);
    gl_lds16(Bw + ((long)(nt0 + w) * KI + it) * 512 + l * 8, Bs + w * 512 + l * 8);
    gl_lds16(Bw + ((long)(nt0 + w + 4) * KI + it) * 512 + l * 8, Bs + (w + 4) * 512 + l * 8);
    __syncthreads();  // compiler emits vmcnt(0) drain
    half8 af[4], bf[4];
#pragma unroll
    for (int i = 0; i < 4; ++i) af[i] = *(const half8*)(As + (wm * 4 + i) * 512 + l * 8);
#pragma unroll
    for (int j = 0; j < 4; ++j) bf[j] = *(const half8*)(Bs + (wn * 4 + j) * 512 + l * 8);
#pragma unroll
    for (int i = 0; i < 4; ++i)
#pragma unroll
      for (int j = 0; j < 4; ++j)
        acc[i][j] = __builtin_amdgcn_mfma_f32_16x16x32_f16(af[i], bf[j], acc[i][j], 0, 0, 0);
  }
#pragma unroll
  for (int i = 0; i < 4; ++i)
#pragma unroll
    for (int j = 0; j < 4; ++j) {
      int mt = mt0 + wm * 4 + i, ntile = nt0 + wn * 4 + j;
      float bv = bias[ntile * 16 + ln];
      half4_t o;
#pragma unroll
      for (int r = 0; r < 4; ++r) o[r] = (_Float16)(acc[i][j][r] + bv);
      *(half4_t*)(C + ((long)mt * NTW + ntile) * 256 + l * 4) = o;  // coalesced 8B
    }
}

// Persistent bidirectional GRU scan over 64 steps.
// grid 256 = d(2) x mtb(8: 64 batch rows) x nt(16: 32 h-cols). 256 thr.
// hbuf: [d*2+parity][512 units][512 halves] fp16 frag layout (512KB/slot).
// All hbuf accesses: relaxed agent-scope atomics (sc1, MALL-coherent).
// Barrier: per-producer flag vector flags[group][nt] = s+1 (monotonic),
// consumers poll all 16 flags with one coalesced 64B load per wave.
__global__ __launch_bounds__(256, 1) void gru_scan_kernel(
    const _Float16* __restrict__ whh,  // [192][16][64][8]
    const float* __restrict__ bhh,     // [3072]
    const _Float16* __restrict__ gx,   // [2048][192][256] (C-frag tiles)
    _Float16* hbuf, _Float16* ys,      // ys: x1 frag [2048][32][64][8] or null
    float* last,                       // [512][1024] f32 or null
    unsigned int* cnt) {               // 16 groups x 16 flags, 64B/group
  __shared__ alignas(16) _Float16 hx[4 * 512];  // 4KB h transpose buffer
  const int bid = blockIdx.x;
  const int d = bid >> 7, mtb = (bid >> 4) & 7, nt = bid & 15;
  const int tid = threadIdx.x, w = tid >> 6, l = tid & 63;
  const int wm = w >> 1, wn = w & 1, lq = l >> 4, ln = l & 15;
  unsigned int* flags = cnt + (d * 8 + mtb) * 16;  // this group's flag vector
  const int hcol = nt * 32 + wn * 16 + ln;  // this lane's h column

  // Whh slice resident in VGPRs for all 64 steps (48 frags = 192 VGPRs)
  half8 bf[3][16];
#pragma unroll
  for (int g = 0; g < 3; ++g) {
    const int tg = d * 96 + g * 32 + nt * 2 + wn;
#pragma unroll
    for (int ks = 0; ks < 16; ++ks)
      bf[g][ks] = *(const half8*)(whh + (long)(tg * 16 + ks) * 512 + l * 8);
  }
  const float bh0 = bhh[d * 1536 + hcol];
  const float bh1 = bhh[d * 1536 + 512 + hcol];
  const float bh2 = bhh[d * 1536 + 1024 + hcol];
  float hreg[2][4] = {{0.f, 0.f, 0.f, 0.f}, {0.f, 0.f, 0.f, 0.f}};  // fp32 master h
  const int mtr0 = mtb * 4 + wm * 2;  // global h row-tile for i=0
  const int qh = (hcol >> 3) & 3, jh = hcol & 7;
  const int ntg0 = d * 96 + nt * 2 + wn;
  const unsigned long long* hb8 = (const unsigned long long*)hbuf;

  float xr[2][4], xz[2][4], xn[2][4];
  auto load_gx = [&](int step, float (&vr)[2][4], float (&vz)[2][4], float (&vn)[2][4]) {
    const int t2 = d ? (63 - step) : step;
    const int rm2 = t2 & 15, tq2 = t2 >> 4;
    const int eoff2 = ((rm2 >> 2) * 16 + ln) * 4 + (rm2 & 3);
#pragma unroll
    for (int i = 0; i < 2; ++i)
#pragma unroll
      for (int r = 0; r < 4; ++r) {
        const int b = (mtr0 + i) * 16 + lq * 4 + r;
        const long gbase = ((long)(b * 4 + tq2) * 192 + ntg0) * 256 + eoff2;
        vr[i][r] = (float)gx[gbase];
        vz[i][r] = (float)gx[gbase + 32 * 256];
        vn[i][r] = (float)gx[gbase + 64 * 256];
      }
  };
  load_gx(0, xr, xz, xn);  // prologue: step-0 gx

  for (int s = 0; s < 64; ++s) {
    const int par = s & 1;
    const unsigned long long* hr8 = hb8 + (long)(d * 2 + par) * 65536;
    const int t_in = d ? (63 - s) : s;
    const int rm = t_in & 15, tq = t_in >> 4;

    float4_t acc[3][2];
#pragma unroll
    for (int g = 0; g < 3; ++g) { acc[g][0] = 0.f; acc[g][1] = 0.f; }
#pragma unroll
    for (int kk = 0; kk < 2; ++kk) {  // 2 chunks of 8 k-steps caps af VGPRs
      half8 af[2][8];
#pragma unroll
      for (int i = 0; i < 2; ++i)
#pragma unroll
        for (int k2 = 0; k2 < 8; ++k2) {
          const unsigned long long* p =
              hr8 + ((long)(mtr0 + i) * 16 + kk * 8 + k2) * 128 + l * 2;
          union { half8 h; unsigned long long q[2]; } fu;
          fu.q[0] = __hip_atomic_load(p, __ATOMIC_RELAXED, __HIP_MEMORY_SCOPE_AGENT);
          fu.q[1] = __hip_atomic_load(p + 1, __ATOMIC_RELAXED, __HIP_MEMORY_SCOPE_AGENT);
          af[i][k2] = fu.h;
        }
#pragma unroll
      for (int k2 = 0; k2 < 8; ++k2)
#pragma unroll
        for (int i = 0; i < 2; ++i)
#pragma unroll
          for (int g = 0; g < 3; ++g)
            acc[g][i] = __builtin_amdgcn_mfma_f32_16x16x32_f16(af[i][k2], bf[g][kk * 8 + k2],
                                                               acc[g][i], 0, 0, 0);
    }

#pragma unroll
    for (int i = 0; i < 2; ++i) {
      const int mtile_i = mtr0 + i;
#pragma unroll
      for (int r = 0; r < 4; ++r) {
        const int b = mtile_i * 16 + lq * 4 + r;  // batch index (C/D row)
        const long gmt = (long)b * 4 + tq;        // gx/x1 row-tile = (b*64+t)>>4
        const float rg = sigm_f(xr[i][r] + acc[0][i][r] + bh0);
        const float zg = sigm_f(xz[i][r] + acc[1][i][r] + bh1);
        const float ng = tanh_f(xn[i][r] + rg * (acc[2][i][r] + bh2));
        const float hv = (1.f - zg) * ng + zg * hreg[i][r];
        hreg[i][r] = hv;
        // stage h for next step into LDS (transpose to contiguous 16B/thread)
        hx[(wm * 2 + i) * 512 + (qh * 16 + lq * 4 + r) * 8 + jh] = (_Float16)hv;
        if (ys != nullptr) {  // layer-0: emit x1 in frag layout (KI=32)
          const int kcol = d * 512 + hcol;
          ys[(gmt * 32 + (kcol >> 5)) * 512 + (((kcol >> 3) & 3) * 16 + rm) * 8 + (kcol & 7)] =
              (_Float16)hv;
        }
        if (last != nullptr && ((d == 0 && s == 63) || (d == 1 && s == 0)))
          last[(long)b * 1024 + d * 512 + hcol] = hv;  // h2[:, t=63, :]
      }
    }
    if (s == 63) break;  // last h never consumed

    __syncthreads();  // LDS transpose complete
    {                 // 16B/thread from LDS -> two 8B sc1 stores (MALL-coherent)
      const int u = tid >> 6, lw = tid & 63;
      union { half8 h; unsigned long long q[2]; } wb;
      wb.h = *(const half8*)(hx + u * 512 + lw * 8);
      unsigned long long* dst = (unsigned long long*)hbuf +
                                (long)(d * 2 + (par ^ 1)) * 65536 +
                                ((long)((mtb * 4 + u) * 16 + nt)) * 128 + lw * 2;
      __hip_atomic_store(dst, wb.q[0], __ATOMIC_RELAXED, __HIP_MEMORY_SCOPE_AGENT);
      __hip_atomic_store(dst + 1, wb.q[1], __ATOMIC_RELAXED, __HIP_MEMORY_SCOPE_AGENT);
    }
    __syncthreads();  // per-wave vmcnt(0) drain => all sc1 stores at MALL

    // signal: one relaxed flag store per block (no RMW chain)
    if (tid == 0)
      __hip_atomic_store(flags + nt, (unsigned int)(s + 1), __ATOMIC_RELAXED,
                         __HIP_MEMORY_SCOPE_AGENT);

    // prefetch next step's gx while waiting on the group (independent of h)
    load_gx(s + 1, xr, xz, xn);

    // per-wave poll: 64B coalesced flag load, all 16 producers >= s+1
    {
      const unsigned int tgt = (unsigned int)(s + 1);
      long guard = 0;
      for (;;) {
        const unsigned int f = __hip_atomic_load(flags + (l & 15), __ATOMIC_RELAXED,
                                                 __HIP_MEMORY_SCOPE_AGENT);
        if (__all((int)(f >= tgt))) break;
        __builtin_amdgcn_s_sleep(1);
        if (++guard > (1L << 24)) break;  // bail out instead of hanging forever
      }
      __builtin_amdgcn_fence(__ATOMIC_ACQUIRE, "workgroup");  // cheap: no cache ops
    }
    // no trailing __syncthreads: each wave proceeds as soon as its poll passes
  }
}

// out[b][o] = last[b] . fc_w[o] + fc_b[o];  512 blocks x 1 wave
__global__ void fc_kernel(const float* __restrict__ lastb, const float* __restrict__ fw,
                          const float* __restrict__ fb, float* __restrict__ out) {
  const int b = blockIdx.x, l = threadIdx.x;
  const float* x = lastb + (long)b * 1024;
  float a0 = 0.f, a1 = 0.f;
  for (int k = l; k < 1024; k += 64) {
    const float v = x[k];
    a0 += v * fw[k];
    a1 += v * fw[1024 + k];
  }
#pragma unroll
  for (int off = 32; off > 0; off >>= 1) {
    a0 += __shfl_down(a0, off, 64);
    a1 += __shfl_down(a1, off, 64);
  }
  if (l == 0) {
    out[b * 2 + 0] = a0 + fb[0];
    out[b * 2 + 1] = a1 + fb[1];
  }
}

extern "C" void kernel_launch(void* const* d_in, const int* in_sizes, int n_in,
                              void* d_out, int out_size, void* d_ws, size_t ws_size,
                              hipStream_t stream) {
  const int* tokens = (const int*)d_in[0];
  const float* emb = (const float*)d_in[1];
  const float* w_ih0 = (const float*)d_in[2];
  const float* w_hh0 = (const float*)d_in[3];
  const float* b_ih0 = (const float*)d_in[4];
  const float* b_hh0 = (const float*)d_in[5];
  const float* w_ih1 = (const float*)d_in[6];
  const float* w_hh1 = (const float*)d_in[7];
  const float* b_ih1 = (const float*)d_in[8];
  const float* b_hh1 = (const float*)d_in[9];
  const float* fc_w = (const float*)d_in[10];
  const float* fc_b = (const float*)d_in[11];
  float* out = (float*)d_out;

  char* ws = (char*)d_ws;
  size_t off = 0;
  auto alloc = [&](size_t bytes) -> void* {
    void* p = ws + off;
    off += (bytes + 255) & ~(size_t)255;
    return p;
  };
  _Float16* W0f = (_Float16*)alloc(192L * 10 * 512 * 2);   // w_ih0 frags (K 300->320)
  _Float16* W1f = (_Float16*)alloc(192L * 32 * 512 * 2);   // w_ih1 frags (K=1024)
  _Float16* Wh0f = (_Float16*)alloc(192L * 16 * 512 * 2);  // w_hh0 frags
  _Float16* Wh1f = (_Float16*)alloc(192L * 16 * 512 * 2);  // w_hh1 frags
  _Float16* x0f = (_Float16*)alloc(2048L * 10 * 512 * 2);  // embedded input frags
  _Float16* x1f = (_Float16*)alloc(2048L * 32 * 512 * 2);  // layer-0 output frags
  _Float16* gxb = (_Float16*)alloc(2048L * 192 * 256 * 2); // gx (shared L0/L1)
  char* hz = ws + off;                                     // memset region start
  _Float16* hbuf = (_Float16*)alloc(4L * 32 * 8192 * 2);   // h double-buffer, 2 dirs
  unsigned int* cnt = (unsigned int*)alloc(4096);          // group barrier flags
  const size_t hz_bytes = 4L * 32 * 8192 * 2 + 4096;
  float* lastb = (float*)alloc(512L * 1024 * 4);
  if (off > ws_size) return;  // workspace too small -> visible absmax failure

  pack_b_kernel<<<dim3(192 * 10 * 64 / 256), 256, 0, stream>>>(w_ih0, W0f, 300, 10);
  pack_b_kernel<<<dim3(192 * 32 * 64 / 256), 256, 0, stream>>>(w_ih1, W1f, 1024, 32);
  pack_b_kernel<<<dim3(192 * 16 * 64 / 256), 256, 0, stream>>>(w_hh0, Wh0f, 512, 16);
  pack_b_kernel<<<dim3(192 * 16 * 64 / 256), 256, 0, stream>>>(w_hh1, Wh1f, 512, 16);
  gather_kernel<<<dim3(2048 * 10 * 64 / 256), 256, 0, stream>>>(tokens, emb, x0f);

  gemm_bt_kernel<<<dim3(24, 256), 256, 0, stream>>>(x0f, W0f, b_ih0, gxb, 10);
  hipMemsetAsync(hz, 0, hz_bytes, stream);
  gru_scan_kernel<<<dim3(256), 256, 0, stream>>>(Wh0f, b_hh0, gxb, hbuf, x1f, nullptr, cnt);

  gemm_bt_kernel<<<dim3(24, 256), 256, 0, stream>>>(x1f, W1f, b_ih1, gxb, 32);
  hipMemsetAsync(hz, 0, hz_bytes, stream);
  gru_scan_kernel<<<dim3(256), 256, 0, stream>>>(Wh1f, b_hh1, gxb, hbuf, nullptr, lastb, cnt);

  fc_kernel<<<dim3(512), 64, 0, stream>>>(lastb, fc_w, fc_b, out);
}

// Round 2
// 1264.368 us; speedup vs baseline: 1.2092x; 1.1368x over previous
//
#include <hip/hip_runtime.h>
#include <stdint.h>

// ============================================================================
// GRU_Model: 2-layer bidirectional GRU, B=512 T=64 E=300 H=512, fp16 MFMA.
//
// Round-3 change (scan kernel only): kill the MALL read amplification.
//  - block = 32 batch rows x 64 h-cols (was 64x32); all 4 waves share the
//    same rows, wave id = 16-col group. h-sharing set per row-slice: 16
//    blocks -> 8, wn duplication removed.
//  - the block stages its 32-row x 512-col h slice (32KB) into LDS ONCE per
//    step (coalesced 16B sc1 loads); MFMA A-frags come from ds_read_b128.
//    MALL h-reads: 32MB/step -> 8MB/step chip-wide.
//  - barrier: 8-producer flag vector per (d,row-group); gx prefetch issued
//    before the poll as in round 2.
// ============================================================================

#define NTW 192   // 3072/16 gate-column tiles (both dirs)
#define MTX 2048  // 32768/16 row tiles (B*T)

typedef _Float16 half8 __attribute__((ext_vector_type(8)));
typedef _Float16 half4_t __attribute__((ext_vector_type(4)));
typedef float float4_t __attribute__((ext_vector_type(4)));

__device__ __forceinline__ void gl_lds16(const void* g, void* l) {
  __builtin_amdgcn_global_load_lds(
      (const __attribute__((address_space(1))) void*)g,
      (__attribute__((address_space(3))) void*)l, 16, 0, 0);
}

__device__ __forceinline__ float sigm_f(float x) { return 1.f / (1.f + __expf(-x)); }
__device__ __forceinline__ float tanh_f(float x) { return 1.f - 2.f / (__expf(2.f * x) + 1.f); }

// f32 (3072, K) row-major -> fp16 frag layout [192][KI][64][8], zero-pad to KI*32
__global__ void pack_b_kernel(const float* __restrict__ src, _Float16* __restrict__ dst,
                              int K, int KI) {
  int gid = blockIdx.x * 256 + threadIdx.x;
  int l = gid & 63, unit = gid >> 6;
  int nt = unit / KI, ks = unit - nt * KI;
  if (nt >= NTW) return;
  int row = nt * 16 + (l & 15);
  int col0 = ks * 32 + ((l >> 4) << 3);
  half8 v;
#pragma unroll
  for (int j = 0; j < 8; ++j) {
    int c = col0 + j;
    v[j] = (c < K) ? (_Float16)src[(long)row * K + c] : (_Float16)0.f;
  }
  *(half8*)(dst + (long)unit * 512 + l * 8) = v;
}

// embedding gather -> x0 frag layout [2048][10][64][8] (K=300 padded to 320)
__global__ void gather_kernel(const int* __restrict__ tokens, const float* __restrict__ emb,
                              _Float16* __restrict__ x0) {
  int gid = blockIdx.x * 256 + threadIdx.x;
  int l = gid & 63, unit = gid >> 6;
  int mt = unit / 10, ks = unit - mt * 10;
  if (mt >= MTX) return;
  int row = mt * 16 + (l & 15);  // row = b*64 + t
  const float* e = emb + (long)tokens[row] * 300;
  int col0 = ks * 32 + ((l >> 4) << 3);
  half8 v;
#pragma unroll
  for (int j = 0; j < 8; ++j) {
    int c = col0 + j;
    v[j] = (c < 300) ? (_Float16)e[c] : (_Float16)0.f;
  }
  *(half8*)(x0 + (long)unit * 512 + l * 8) = v;
}

// C(M=32768,N=3072) = A(M,K) * B(N,K)^T + bias[n];  A,B frag-layout fp16,
// C in C-frag tile layout [mtile][ntile][256] fp16.  grid (24, 256), 256 thr.
__global__ __launch_bounds__(256) void gemm_bt_kernel(
    const _Float16* __restrict__ A, const _Float16* __restrict__ Bw,
    const float* __restrict__ bias, _Float16* __restrict__ C, int KI) {
  __shared__ _Float16 As[8 * 512];
  __shared__ _Float16 Bs[8 * 512];
  const int bx = blockIdx.x, by = blockIdx.y;
  const int tid = threadIdx.x, w = tid >> 6, l = tid & 63;
  const int wm = w >> 1, wn = w & 1, ln = l & 15;
  const int mt0 = by * 8, nt0 = bx * 8;
  float4_t acc[4][4];
#pragma unroll
  for (int i = 0; i < 4; ++i)
#pragma unroll
    for (int j = 0; j < 4; ++j) acc[i][j] = 0.f;
  for (int it = 0; it < KI; ++it) {
    __syncthreads();  // protect LDS from previous iter's readers
    gl_lds16(A + ((long)(mt0 + w) * KI + it) * 512 + l * 8, As + w * 512 + l * 8);
    gl_lds16(A + ((long)(mt0 + w + 4) * KI + it) * 512 + l * 8, As + (w + 4) * 512 + l * 8);
    gl_lds16(Bw + ((long)(nt0 + w) * KI + it) * 512 + l * 8, Bs + w * 512 + l * 8);
    gl_lds16(Bw + ((long)(nt0 + w + 4) * KI + it) * 512 + l * 8, Bs + (w + 4) * 512 + l * 8);
    __syncthreads();  // compiler emits vmcnt(0) drain
    half8 af[4], bf[4];
#pragma unroll
    for (int i = 0; i < 4; ++i) af[i] = *(const half8*)(As + (wm * 4 + i) * 512 + l * 8);
#pragma unroll
    for (int j = 0; j < 4; ++j) bf[j] = *(const half8*)(Bs + (wn * 4 + j) * 512 + l * 8);
#pragma unroll
    for (int i = 0; i < 4; ++i)
#pragma unroll
      for (int j = 0; j < 4; ++j)
        acc[i][j] = __builtin_amdgcn_mfma_f32_16x16x32_f16(af[i], bf[j], acc[i][j], 0, 0, 0);
  }
#pragma unroll
  for (int i = 0; i < 4; ++i)
#pragma unroll
    for (int j = 0; j < 4; ++j) {
      int mt = mt0 + wm * 4 + i, ntile = nt0 + wn * 4 + j;
      float bv = bias[ntile * 16 + ln];
      half4_t o;
#pragma unroll
      for (int r = 0; r < 4; ++r) o[r] = (_Float16)(acc[i][j][r] + bv);
      *(half4_t*)(C + ((long)mt * NTW + ntile) * 256 + l * 4) = o;  // coalesced 8B
    }
}

// Persistent bidirectional GRU scan over 64 steps.
// grid 256 = d(2) x mtg(16: 32 batch rows) x ntb(8: 64 h-cols). 256 thr.
// Wave w (0..3) = 16-col group; all waves share the block's 2 row-tiles.
// hbuf: [d*2+parity][512 units][512 halves] fp16 frag layout (512KB/slot).
// Per step the block stages its 32-row x 512-col h slice (32KB) into LDS
// with coalesced sc1 loads, then feeds MFMA A-frags from LDS.
__global__ __launch_bounds__(256, 1) void gru_scan_kernel(
    const _Float16* __restrict__ whh,  // [192][16][64][8]
    const float* __restrict__ bhh,     // [3072]
    const _Float16* __restrict__ gx,   // [2048][192][256] (C-frag tiles)
    _Float16* hbuf, _Float16* ys,      // ys: x1 frag [2048][32][64][8] or null
    float* last,                       // [512][1024] f32 or null
    unsigned int* cnt) {               // 32 groups x 16 flags, 64B/group
  __shared__ alignas(16) _Float16 hs[32 * 512];  // 32KB staged h (frag layout)
  __shared__ alignas(16) _Float16 hx[4 * 512];   // 4KB h transpose buffer
  const int bid = blockIdx.x;
  const int d = bid >> 7, mtg = (bid >> 3) & 15, ntb = bid & 7;
  const int tid = threadIdx.x, w = tid >> 6, l = tid & 63;
  const int lq = l >> 4, ln = l & 15;
  unsigned int* flags = cnt + (d * 16 + mtg) * 16;  // this group's flag vector
  const int hcol = ntb * 64 + w * 16 + ln;          // this lane's h column

  // Whh slice resident in VGPRs for all 64 steps (48 frags = 192 VGPRs)
  half8 bf[3][16];
#pragma unroll
  for (int g = 0; g < 3; ++g) {
    const int tg = d * 96 + g * 32 + ntb * 4 + w;
#pragma unroll
    for (int ks = 0; ks < 16; ++ks)
      bf[g][ks] = *(const half8*)(whh + (long)(tg * 16 + ks) * 512 + l * 8);
  }
  const float bh0 = bhh[d * 1536 + hcol];
  const float bh1 = bhh[d * 1536 + 512 + hcol];
  const float bh2 = bhh[d * 1536 + 1024 + hcol];
  float hreg[2][4] = {{0.f, 0.f, 0.f, 0.f}, {0.f, 0.f, 0.f, 0.f}};  // fp32 master h
  const int mtr0 = mtg * 2;  // global h row-tile for i=0 (2 rowtiles/block)
  const int ntg0 = d * 96 + ntb * 4 + w;  // gate-r ntile for this wave's cols
  const unsigned long long* hb8 = (const unsigned long long*)hbuf;
  unsigned long long* lds64 = (unsigned long long*)hs;

  float xr[2][4], xz[2][4], xn[2][4];
  auto load_gx = [&](int step, float (&vr)[2][4], float (&vz)[2][4], float (&vn)[2][4]) {
    const int t2 = d ? (63 - step) : step;
    const int rm2 = t2 & 15, tq2 = t2 >> 4;
    const int eoff2 = ((rm2 >> 2) * 16 + ln) * 4 + (rm2 & 3);
#pragma unroll
    for (int i = 0; i < 2; ++i)
#pragma unroll
      for (int r = 0; r < 4; ++r) {
        const int b = (mtr0 + i) * 16 + lq * 4 + r;
        const long gbase = ((long)(b * 4 + tq2) * 192 + ntg0) * 256 + eoff2;
        vr[i][r] = (float)gx[gbase];
        vz[i][r] = (float)gx[gbase + 32 * 256];
        vn[i][r] = (float)gx[gbase + 64 * 256];
      }
  };
  load_gx(0, xr, xz, xn);  // prologue: step-0 gx

  for (int s = 0; s < 64; ++s) {
    const int par = s & 1;
    const int t_in = d ? (63 - s) : s;
    const int rm = t_in & 15, tq = t_in >> 4;

    // ---- stage this step's h slice (32 rowtile-frags, 32KB) into LDS ----
    {
      const unsigned long long* src =
          hb8 + (long)(d * 2 + par) * 65536 + (long)mtg * 4096;
#pragma unroll
      for (int rr = 0; rr < 2; ++rr) {
        unsigned long long t0[8];
#pragma unroll
        for (int j = 0; j < 4; ++j) {
          const int f = (rr * 4 + j) * 256 + tid;
          t0[j * 2] = __hip_atomic_load(src + (long)f * 2, __ATOMIC_RELAXED,
                                        __HIP_MEMORY_SCOPE_AGENT);
          t0[j * 2 + 1] = __hip_atomic_load(src + (long)f * 2 + 1, __ATOMIC_RELAXED,
                                            __HIP_MEMORY_SCOPE_AGENT);
        }
#pragma unroll
        for (int j = 0; j < 4; ++j) {
          const int f = (rr * 4 + j) * 256 + tid;
          lds64[f * 2] = t0[j * 2];
          lds64[f * 2 + 1] = t0[j * 2 + 1];
        }
      }
    }
    __syncthreads();  // h slice staged

    float4_t acc[3][2];
#pragma unroll
    for (int g = 0; g < 3; ++g) { acc[g][0] = 0.f; acc[g][1] = 0.f; }
#pragma unroll
    for (int kk = 0; kk < 2; ++kk) {  // 2 chunks of 8 k-steps caps af VGPRs
      half8 af[2][8];
#pragma unroll
      for (int i = 0; i < 2; ++i)
#pragma unroll
        for (int k2 = 0; k2 < 8; ++k2)
          af[i][k2] = *(const half8*)(hs + (i * 16 + kk * 8 + k2) * 512 + l * 8);
#pragma unroll
      for (int k2 = 0; k2 < 8; ++k2)
#pragma unroll
        for (int i = 0; i < 2; ++i)
#pragma unroll
          for (int g = 0; g < 3; ++g)
            acc[g][i] = __builtin_amdgcn_mfma_f32_16x16x32_f16(af[i][k2], bf[g][kk * 8 + k2],
                                                               acc[g][i], 0, 0, 0);
    }

#pragma unroll
    for (int i = 0; i < 2; ++i) {
      const int mtile_i = mtr0 + i;
#pragma unroll
      for (int r = 0; r < 4; ++r) {
        const int b = mtile_i * 16 + lq * 4 + r;  // batch index (C/D row)
        const long gmt = (long)b * 4 + tq;        // gx/x1 row-tile = (b*64+t)>>4
        const float rg = sigm_f(xr[i][r] + acc[0][i][r] + bh0);
        const float zg = sigm_f(xz[i][r] + acc[1][i][r] + bh1);
        const float ng = tanh_f(xn[i][r] + rg * (acc[2][i][r] + bh2));
        const float hv = (1.f - zg) * ng + zg * hreg[i][r];
        hreg[i][r] = hv;
        // stage h for next step into LDS (transpose to frag-chunk layout)
        // unit = rowtile(i)*2 + local-ks(w>>1); lane_t = colgroup*16 + row
        hx[(i * 2 + (w >> 1)) * 512 + (((w & 1) * 2 + (ln >> 3)) * 16 + lq * 4 + r) * 8 +
           (ln & 7)] = (_Float16)hv;
        if (ys != nullptr) {  // layer-0: emit x1 in frag layout (KI=32)
          const int kcol = d * 512 + hcol;
          ys[(gmt * 32 + (kcol >> 5)) * 512 + (((kcol >> 3) & 3) * 16 + rm) * 8 + (kcol & 7)] =
              (_Float16)hv;
        }
        if (last != nullptr && ((d == 0 && s == 63) || (d == 1 && s == 0)))
          last[(long)b * 1024 + d * 512 + hcol] = hv;  // h2[:, t=63, :]
      }
    }
    if (s == 63) break;  // last h never consumed

    __syncthreads();  // LDS transpose complete
    {                 // 16B/thread from LDS -> two 8B sc1 stores (MALL-coherent)
      const int u = tid >> 6, lw = tid & 63;
      union { half8 h; unsigned long long q[2]; } wb;
      wb.h = *(const half8*)(hx + u * 512 + lw * 8);
      unsigned long long* dst = (unsigned long long*)hbuf +
                                (long)(d * 2 + (par ^ 1)) * 65536 +
                                ((long)((mtg * 2 + (u >> 1)) * 16 + ntb * 2 + (u & 1))) * 128 +
                                lw * 2;
      __hip_atomic_store(dst, wb.q[0], __ATOMIC_RELAXED, __HIP_MEMORY_SCOPE_AGENT);
      __hip_atomic_store(dst + 1, wb.q[1], __ATOMIC_RELAXED, __HIP_MEMORY_SCOPE_AGENT);
    }
    __syncthreads();  // per-wave vmcnt(0) drain => all sc1 stores at MALL

    // signal: one relaxed flag store per block (no RMW chain)
    if (tid == 0)
      __hip_atomic_store(flags + ntb, (unsigned int)(s + 1), __ATOMIC_RELAXED,
                         __HIP_MEMORY_SCOPE_AGENT);

    // prefetch next step's gx while waiting on the group (independent of h)
    load_gx(s + 1, xr, xz, xn);

    // per-wave poll: 8 producer flags, coalesced load + __all
    {
      const unsigned int tgt = (unsigned int)(s + 1);
      long guard = 0;
      for (;;) {
        const unsigned int f = __hip_atomic_load(flags + (l & 7), __ATOMIC_RELAXED,
                                                 __HIP_MEMORY_SCOPE_AGENT);
        if (__all((int)(f >= tgt))) break;
        __builtin_amdgcn_s_sleep(1);
        if (++guard > (1L << 24)) break;  // bail out instead of hanging forever
      }
      __builtin_amdgcn_fence(__ATOMIC_ACQUIRE, "workgroup");  // cheap: no cache ops
    }
    // no trailing __syncthreads: the staging-phase __syncthreads orders waves
  }
}

// out[b][o] = last[b] . fc_w[o] + fc_b[o];  512 blocks x 1 wave
__global__ void fc_kernel(const float* __restrict__ lastb, const float* __restrict__ fw,
                          const float* __restrict__ fb, float* __restrict__ out) {
  const int b = blockIdx.x, l = threadIdx.x;
  const float* x = lastb + (long)b * 1024;
  float a0 = 0.f, a1 = 0.f;
  for (int k = l; k < 1024; k += 64) {
    const float v = x[k];
    a0 += v * fw[k];
    a1 += v * fw[1024 + k];
  }
#pragma unroll
  for (int off = 32; off > 0; off >>= 1) {
    a0 += __shfl_down(a0, off, 64);
    a1 += __shfl_down(a1, off, 64);
  }
  if (l == 0) {
    out[b * 2 + 0] = a0 + fb[0];
    out[b * 2 + 1] = a1 + fb[1];
  }
}

extern "C" void kernel_launch(void* const* d_in, const int* in_sizes, int n_in,
                              void* d_out, int out_size, void* d_ws, size_t ws_size,
                              hipStream_t stream) {
  const int* tokens = (const int*)d_in[0];
  const float* emb = (const float*)d_in[1];
  const float* w_ih0 = (const float*)d_in[2];
  const float* w_hh0 = (const float*)d_in[3];
  const float* b_ih0 = (const float*)d_in[4];
  const float* b_hh0 = (const float*)d_in[5];
  const float* w_ih1 = (const float*)d_in[6];
  const float* w_hh1 = (const float*)d_in[7];
  const float* b_ih1 = (const float*)d_in[8];
  const float* b_hh1 = (const float*)d_in[9];
  const float* fc_w = (const float*)d_in[10];
  const float* fc_b = (const float*)d_in[11];
  float* out = (float*)d_out;

  char* ws = (char*)d_ws;
  size_t off = 0;
  auto alloc = [&](size_t bytes) -> void* {
    void* p = ws + off;
    off += (bytes + 255) & ~(size_t)255;
    return p;
  };
  _Float16* W0f = (_Float16*)alloc(192L * 10 * 512 * 2);   // w_ih0 frags (K 300->320)
  _Float16* W1f = (_Float16*)alloc(192L * 32 * 512 * 2);   // w_ih1 frags (K=1024)
  _Float16* Wh0f = (_Float16*)alloc(192L * 16 * 512 * 2);  // w_hh0 frags
  _Float16* Wh1f = (_Float16*)alloc(192L * 16 * 512 * 2);  // w_hh1 frags
  _Float16* x0f = (_Float16*)alloc(2048L * 10 * 512 * 2);  // embedded input frags
  _Float16* x1f = (_Float16*)alloc(2048L * 32 * 512 * 2);  // layer-0 output frags
  _Float16* gxb = (_Float16*)alloc(2048L * 192 * 256 * 2); // gx (shared L0/L1)
  char* hz = ws + off;                                     // memset region start
  _Float16* hbuf = (_Float16*)alloc(4L * 32 * 8192 * 2);   // h double-buffer, 2 dirs
  unsigned int* cnt = (unsigned int*)alloc(4096);          // group barrier flags
  const size_t hz_bytes = 4L * 32 * 8192 * 2 + 4096;
  float* lastb = (float*)alloc(512L * 1024 * 4);
  if (off > ws_size) return;  // workspace too small -> visible absmax failure

  pack_b_kernel<<<dim3(192 * 10 * 64 / 256), 256, 0, stream>>>(w_ih0, W0f, 300, 10);
  pack_b_kernel<<<dim3(192 * 32 * 64 / 256), 256, 0, stream>>>(w_ih1, W1f, 1024, 32);
  pack_b_kernel<<<dim3(192 * 16 * 64 / 256), 256, 0, stream>>>(w_hh0, Wh0f, 512, 16);
  pack_b_kernel<<<dim3(192 * 16 * 64 / 256), 256, 0, stream>>>(w_hh1, Wh1f, 512, 16);
  gather_kernel<<<dim3(2048 * 10 * 64 / 256), 256, 0, stream>>>(tokens, emb, x0f);

  gemm_bt_kernel<<<dim3(24, 256), 256, 0, stream>>>(x0f, W0f, b_ih0, gxb, 10);
  hipMemsetAsync(hz, 0, hz_bytes, stream);
  gru_scan_kernel<<<dim3(256), 256, 0, stream>>>(Wh0f, b_hh0, gxb, hbuf, x1f, nullptr, cnt);

  gemm_bt_kernel<<<dim3(24, 256), 256, 0, stream>>>(x1f, W1f, b_ih1, gxb, 32);
  hipMemsetAsync(hz, 0, hz_bytes, stream);
  gru_scan_kernel<<<dim3(256), 256, 0, stream>>>(Wh1f, b_hh1, gxb, hbuf, nullptr, lastb, cnt);

  fc_kernel<<<dim3(512), 64, 0, stream>>>(lastb, fc_w, fc_b, out);
}

// Round 3
// 1218.329 us; speedup vs baseline: 1.2549x; 1.0378x over previous
//
#include <hip/hip_runtime.h>
#include <stdint.h>

// ============================================================================
// GRU_Model: 2-layer bidirectional GRU, B=512 T=64 E=300 H=512, fp16 MFMA.
//
// Round-4 change (scan kernel only): dual independent chains per block to
// hide the cross-block h-exchange latency.
//  - block = d x mpair x ntb handles TWO independent 16-row chains
//    (rowtiles rA=2*mp, rB=2*mp+1), each with its own 8-producer flag group.
//  - schedule interleaves the chains: while chain A's h store drains / peers
//    poll, chain B's MFMA+gates run, and vice versa. Chain A's flag is also
//    raised mid-step (right after its store drain) so peers wait less.
//  - same arithmetic, same element order -> bit-identical numerics.
// ============================================================================

#define NTW 192   // 3072/16 gate-column tiles (both dirs)
#define MTX 2048  // 32768/16 row tiles (B*T)

typedef _Float16 half8 __attribute__((ext_vector_type(8)));
typedef _Float16 half4_t __attribute__((ext_vector_type(4)));
typedef float float4_t __attribute__((ext_vector_type(4)));

__device__ __forceinline__ void gl_lds16(const void* g, void* l) {
  __builtin_amdgcn_global_load_lds(
      (const __attribute__((address_space(1))) void*)g,
      (__attribute__((address_space(3))) void*)l, 16, 0, 0);
}

__device__ __forceinline__ float sigm_f(float x) { return 1.f / (1.f + __expf(-x)); }
__device__ __forceinline__ float tanh_f(float x) { return 1.f - 2.f / (__expf(2.f * x) + 1.f); }

// f32 (3072, K) row-major -> fp16 frag layout [192][KI][64][8], zero-pad to KI*32
__global__ void pack_b_kernel(const float* __restrict__ src, _Float16* __restrict__ dst,
                              int K, int KI) {
  int gid = blockIdx.x * 256 + threadIdx.x;
  int l = gid & 63, unit = gid >> 6;
  int nt = unit / KI, ks = unit - nt * KI;
  if (nt >= NTW) return;
  int row = nt * 16 + (l & 15);
  int col0 = ks * 32 + ((l >> 4) << 3);
  half8 v;
#pragma unroll
  for (int j = 0; j < 8; ++j) {
    int c = col0 + j;
    v[j] = (c < K) ? (_Float16)src[(long)row * K + c] : (_Float16)0.f;
  }
  *(half8*)(dst + (long)unit * 512 + l * 8) = v;
}

// embedding gather -> x0 frag layout [2048][10][64][8] (K=300 padded to 320)
__global__ void gather_kernel(const int* __restrict__ tokens, const float* __restrict__ emb,
                              _Float16* __restrict__ x0) {
  int gid = blockIdx.x * 256 + threadIdx.x;
  int l = gid & 63, unit = gid >> 6;
  int mt = unit / 10, ks = unit - mt * 10;
  if (mt >= MTX) return;
  int row = mt * 16 + (l & 15);  // row = b*64 + t
  const float* e = emb + (long)tokens[row] * 300;
  int col0 = ks * 32 + ((l >> 4) << 3);
  half8 v;
#pragma unroll
  for (int j = 0; j < 8; ++j) {
    int c = col0 + j;
    v[j] = (c < 300) ? (_Float16)e[c] : (_Float16)0.f;
  }
  *(half8*)(x0 + (long)unit * 512 + l * 8) = v;
}

// C(M=32768,N=3072) = A(M,K) * B(N,K)^T + bias[n];  A,B frag-layout fp16,
// C in C-frag tile layout [mtile][ntile][256] fp16.  grid (24, 256), 256 thr.
__global__ __launch_bounds__(256) void gemm_bt_kernel(
    const _Float16* __restrict__ A, const _Float16* __restrict__ Bw,
    const float* __restrict__ bias, _Float16* __restrict__ C, int KI) {
  __shared__ _Float16 As[8 * 512];
  __shared__ _Float16 Bs[8 * 512];
  const int bx = blockIdx.x, by = blockIdx.y;
  const int tid = threadIdx.x, w = tid >> 6, l = tid & 63;
  const int wm = w >> 1, wn = w & 1, ln = l & 15;
  const int mt0 = by * 8, nt0 = bx * 8;
  float4_t acc[4][4];
#pragma unroll
  for (int i = 0; i < 4; ++i)
#pragma unroll
    for (int j = 0; j < 4; ++j) acc[i][j] = 0.f;
  for (int it = 0; it < KI; ++it) {
    __syncthreads();  // protect LDS from previous iter's readers
    gl_lds16(A + ((long)(mt0 + w) * KI + it) * 512 + l * 8, As + w * 512 + l * 8);
    gl_lds16(A + ((long)(mt0 + w + 4) * KI + it) * 512 + l * 8, As + (w + 4) * 512 + l * 8);
    gl_lds16(Bw + ((long)(nt0 + w) * KI + it) * 512 + l * 8, Bs + w * 512 + l * 8);
    gl_lds16(Bw + ((long)(nt0 + w + 4) * KI + it) * 512 + l * 8, Bs + (w + 4) * 512 + l * 8);
    __syncthreads();  // compiler emits vmcnt(0) drain
    half8 af[4], bf[4];
#pragma unroll
    for (int i = 0; i < 4; ++i) af[i] = *(const half8*)(As + (wm * 4 + i) * 512 + l * 8);
#pragma unroll
    for (int j = 0; j < 4; ++j) bf[j] = *(const half8*)(Bs + (wn * 4 + j) * 512 + l * 8);
#pragma unroll
    for (int i = 0; i < 4; ++i)
#pragma unroll
      for (int j = 0; j < 4; ++j)
        acc[i][j] = __builtin_amdgcn_mfma_f32_16x16x32_f16(af[i], bf[j], acc[i][j], 0, 0, 0);
  }
#pragma unroll
  for (int i = 0; i < 4; ++i)
#pragma unroll
    for (int j = 0; j < 4; ++j) {
      int mt = mt0 + wm * 4 + i, ntile = nt0 + wn * 4 + j;
      float bv = bias[ntile * 16 + ln];
      half4_t o;
#pragma unroll
      for (int r = 0; r < 4; ++r) o[r] = (_Float16)(acc[i][j][r] + bv);
      *(half4_t*)(C + ((long)mt * NTW + ntile) * 256 + l * 4) = o;  // coalesced 8B
    }
}

// Persistent bidirectional GRU scan over 64 steps, dual 16-row chains/block.
// grid 256 = d(2) x mp(16) x ntb(8). Chains: rowtiles rA=2mp, rB=2mp+1.
// Wave w (0..3) = 16-col group; all waves share both chains' rows.
// hbuf: [d*2+parity][32 rowtiles][16 colfrags][1KB] fp16 frag layout.
// Barrier: per (d,rowtile) flag group, 8 producers (ntb), relaxed sc1.
__global__ __launch_bounds__(256, 1) void gru_scan_kernel(
    const _Float16* __restrict__ whh,  // [192][16][64][8]
    const float* __restrict__ bhh,     // [3072]
    const _Float16* __restrict__ gx,   // [2048][192][256] (C-frag tiles)
    _Float16* hbuf, _Float16* ys,      // ys: x1 frag [2048][32][64][8] or null
    float* last,                       // [512][1024] f32 or null
    unsigned int* cnt) {               // 64 groups x 16 flags, 64B/group
  __shared__ alignas(16) _Float16 hsA[16 * 512];  // 16KB chain-A h (frag layout)
  __shared__ alignas(16) _Float16 hsB[16 * 512];  // 16KB chain-B h
  __shared__ alignas(16) _Float16 hx[2 * 512];    // 2KB transpose buf (shared A/B)
  const int bid = blockIdx.x;
  const int d = bid >> 7, mp = (bid >> 3) & 15, ntb = bid & 7;
  const int rA = mp * 2, rB = rA + 1;
  const int tid = threadIdx.x, w = tid >> 6, l = tid & 63;
  const int lq = l >> 4, ln = l & 15;
  unsigned int* flagsA = cnt + (d * 32 + rA) * 16;
  unsigned int* flagsB = cnt + (d * 32 + rB) * 16;
  const int hcol = ntb * 64 + w * 16 + ln;  // this lane's h column

  // Whh slice resident for all 64 steps (48 frags, shared by both chains)
  half8 bf[3][16];
#pragma unroll
  for (int g = 0; g < 3; ++g) {
    const int tg = d * 96 + g * 32 + ntb * 4 + w;
#pragma unroll
    for (int ks = 0; ks < 16; ++ks)
      bf[g][ks] = *(const half8*)(whh + (long)(tg * 16 + ks) * 512 + l * 8);
  }
  const float bh0 = bhh[d * 1536 + hcol];
  const float bh1 = bhh[d * 1536 + 512 + hcol];
  const float bh2 = bhh[d * 1536 + 1024 + hcol];
  float hrA[4] = {0.f, 0.f, 0.f, 0.f};  // fp32 master h, chain A
  float hrB[4] = {0.f, 0.f, 0.f, 0.f};  // fp32 master h, chain B
  const int ntg0 = d * 96 + ntb * 4 + w;
  const unsigned long long* hb8 = (const unsigned long long*)hbuf;
  unsigned long long* hb8w = (unsigned long long*)hbuf;
  unsigned long long* lA64 = (unsigned long long*)hsA;
  unsigned long long* lB64 = (unsigned long long*)hsB;
  const unsigned long long* hx64 = (const unsigned long long*)hx;

  float xrA[4], xzA[4], xnA[4], xrB[4], xzB[4], xnB[4];
  auto load_gx = [&](int step, int rc, float (&vr)[4], float (&vz)[4], float (&vn)[4]) {
    const int t2 = d ? (63 - step) : step;
    const int rm2 = t2 & 15, tq2 = t2 >> 4;
    const int eoff2 = ((rm2 >> 2) * 16 + ln) * 4 + (rm2 & 3);
#pragma unroll
    for (int r = 0; r < 4; ++r) {
      const int b = rc * 16 + lq * 4 + r;
      const long gbase = ((long)(b * 4 + tq2) * 192 + ntg0) * 256 + eoff2;
      vr[r] = (float)gx[gbase];
      vz[r] = (float)gx[gbase + 32 * 256];
      vn[r] = (float)gx[gbase + 64 * 256];
    }
  };
  load_gx(0, rA, xrA, xzA, xnA);  // prologue: step-0 gx, both chains
  load_gx(0, rB, xrB, xzB, xnB);

  auto poll = [&](unsigned int* flags, unsigned int tgt) {
    long guard = 0;
    for (;;) {
      const unsigned int f = __hip_atomic_load(flags + (l & 7), __ATOMIC_RELAXED,
                                               __HIP_MEMORY_SCOPE_AGENT);
      if (__all((int)(f >= tgt))) break;
      __builtin_amdgcn_s_sleep(1);
      if (++guard > (1L << 24)) break;  // bail out instead of hanging forever
    }
  };

  for (int s = 0; s < 64; ++s) {
    const int par = s & 1;
    const int t_in = d ? (63 - s) : s;
    const int rm = t_in & 15, tq = t_in >> 4;
    const unsigned long long* src = hb8 + (long)(d * 2 + par) * 65536;

    // ---- wait for both chains' h(s), then issue both stage loads ----
    poll(flagsA, (unsigned int)s);
    poll(flagsB, (unsigned int)s);
    __builtin_amdgcn_fence(__ATOMIC_ACQUIRE, "workgroup");  // cheap: no cache ops
    unsigned long long ta[8], tb[8];
#pragma unroll
    for (int j = 0; j < 8; ++j)
      ta[j] = __hip_atomic_load(src + (long)rA * 2048 + j * 256 + tid, __ATOMIC_RELAXED,
                                __HIP_MEMORY_SCOPE_AGENT);
#pragma unroll
    for (int j = 0; j < 8; ++j)
      tb[j] = __hip_atomic_load(src + (long)rB * 2048 + j * 256 + tid, __ATOMIC_RELAXED,
                                __HIP_MEMORY_SCOPE_AGENT);
#pragma unroll
    for (int j = 0; j < 8; ++j) lA64[j * 256 + tid] = ta[j];
    __syncthreads();  // hsA staged (tb still in flight)

    // ---- chain A MFMA ----
    float4_t accA[3];
    accA[0] = 0.f; accA[1] = 0.f; accA[2] = 0.f;
#pragma unroll
    for (int kk = 0; kk < 2; ++kk) {
      half8 af[8];
#pragma unroll
      for (int k2 = 0; k2 < 8; ++k2)
        af[k2] = *(const half8*)(hsA + (kk * 8 + k2) * 512 + l * 8);
#pragma unroll
      for (int k2 = 0; k2 < 8; ++k2)
#pragma unroll
        for (int g = 0; g < 3; ++g)
          accA[g] = __builtin_amdgcn_mfma_f32_16x16x32_f16(af[k2], bf[g][kk * 8 + k2],
                                                           accA[g], 0, 0, 0);
    }
    // stage chain B into LDS (waits tb only)
#pragma unroll
    for (int j = 0; j < 8; ++j) lB64[j * 256 + tid] = tb[j];

    // ---- chain A gates ----
#pragma unroll
    for (int r = 0; r < 4; ++r) {
      const int b = rA * 16 + lq * 4 + r;
      const long gmt = (long)b * 4 + tq;
      const float rg = sigm_f(xrA[r] + accA[0][r] + bh0);
      const float zg = sigm_f(xzA[r] + accA[1][r] + bh1);
      const float ng = tanh_f(xnA[r] + rg * (accA[2][r] + bh2));
      const float hv = (1.f - zg) * ng + zg * hrA[r];
      hrA[r] = hv;
      hx[(w >> 1) * 512 + (((w & 1) * 2 + (ln >> 3)) * 16 + lq * 4 + r) * 8 + (ln & 7)] =
          (_Float16)hv;
      if (ys != nullptr) {
        const int kcol = d * 512 + hcol;
        ys[(gmt * 32 + (kcol >> 5)) * 512 + (((kcol >> 3) & 3) * 16 + rm) * 8 + (kcol & 7)] =
            (_Float16)hv;
      }
      if (last != nullptr && ((d == 0 && s == 63) || (d == 1 && s == 0)))
        last[(long)b * 1024 + d * 512 + hcol] = hv;
    }
    __syncthreads();  // hsB staged + hxA visible

    if (s < 63) {  // store chain A h(s+1): 8B/thread, coalesced sc1
      const unsigned long long qa = hx64[tid];
      unsigned long long* dst = hb8w + (long)(d * 2 + (par ^ 1)) * 65536 +
                                (long)rA * 2048 + (ntb * 2 + (tid >> 7)) * 128 + (tid & 127);
      __hip_atomic_store(dst, qa, __ATOMIC_RELAXED, __HIP_MEMORY_SCOPE_AGENT);
    }

    // ---- chain B MFMA (overlaps A's store drain) ----
    float4_t accB[3];
    accB[0] = 0.f; accB[1] = 0.f; accB[2] = 0.f;
#pragma unroll
    for (int kk = 0; kk < 2; ++kk) {
      half8 af[8];
#pragma unroll
      for (int k2 = 0; k2 < 8; ++k2)
        af[k2] = *(const half8*)(hsB + (kk * 8 + k2) * 512 + l * 8);
#pragma unroll
      for (int k2 = 0; k2 < 8; ++k2)
#pragma unroll
        for (int g = 0; g < 3; ++g)
          accB[g] = __builtin_amdgcn_mfma_f32_16x16x32_f16(af[k2], bf[g][kk * 8 + k2],
                                                           accB[g], 0, 0, 0);
    }
    __syncthreads();  // per-wave vmcnt(0) drain => A stores at MALL
    if (tid == 0 && s < 63)  // early A flag: peers can stage A while we do B
      __hip_atomic_store(flagsA + ntb, (unsigned int)(s + 1), __ATOMIC_RELAXED,
                         __HIP_MEMORY_SCOPE_AGENT);

    // ---- chain B gates ----
#pragma unroll
    for (int r = 0; r < 4; ++r) {
      const int b = rB * 16 + lq * 4 + r;
      const long gmt = (long)b * 4 + tq;
      const float rg = sigm_f(xrB[r] + accB[0][r] + bh0);
      const float zg = sigm_f(xzB[r] + accB[1][r] + bh1);
      const float ng = tanh_f(xnB[r] + rg * (accB[2][r] + bh2));
      const float hv = (1.f - zg) * ng + zg * hrB[r];
      hrB[r] = hv;
      hx[(w >> 1) * 512 + (((w & 1) * 2 + (ln >> 3)) * 16 + lq * 4 + r) * 8 + (ln & 7)] =
          (_Float16)hv;
      if (ys != nullptr) {
        const int kcol = d * 512 + hcol;
        ys[(gmt * 32 + (kcol >> 5)) * 512 + (((kcol >> 3) & 3) * 16 + rm) * 8 + (kcol & 7)] =
            (_Float16)hv;
      }
      if (last != nullptr && ((d == 0 && s == 63) || (d == 1 && s == 0)))
        last[(long)b * 1024 + d * 512 + hcol] = hv;
    }
    if (s == 63) break;  // last h never consumed

    __syncthreads();  // hxB visible
    {                 // store chain B h(s+1)
      const unsigned long long qb = hx64[tid];
      unsigned long long* dst = hb8w + (long)(d * 2 + (par ^ 1)) * 65536 +
                                (long)rB * 2048 + (ntb * 2 + (tid >> 7)) * 128 + (tid & 127);
      __hip_atomic_store(dst, qb, __ATOMIC_RELAXED, __HIP_MEMORY_SCOPE_AGENT);
    }
    __syncthreads();  // per-wave vmcnt(0) drain => B stores at MALL
    if (tid == 0)
      __hip_atomic_store(flagsB + ntb, (unsigned int)(s + 1), __ATOMIC_RELAXED,
                         __HIP_MEMORY_SCOPE_AGENT);

    // prefetch next step's gx for both chains (flies during next poll)
    load_gx(s + 1, rA, xrA, xzA, xnA);
    load_gx(s + 1, rB, xrB, xzB, xnB);
  }
}

// out[b][o] = last[b] . fc_w[o] + fc_b[o];  512 blocks x 1 wave
__global__ void fc_kernel(const float* __restrict__ lastb, const float* __restrict__ fw,
                          const float* __restrict__ fb, float* __restrict__ out) {
  const int b = blockIdx.x, l = threadIdx.x;
  const float* x = lastb + (long)b * 1024;
  float a0 = 0.f, a1 = 0.f;
  for (int k = l; k < 1024; k += 64) {
    const float v = x[k];
    a0 += v * fw[k];
    a1 += v * fw[1024 + k];
  }
#pragma unroll
  for (int off = 32; off > 0; off >>= 1) {
    a0 += __shfl_down(a0, off, 64);
    a1 += __shfl_down(a1, off, 64);
  }
  if (l == 0) {
    out[b * 2 + 0] = a0 + fb[0];
    out[b * 2 + 1] = a1 + fb[1];
  }
}

extern "C" void kernel_launch(void* const* d_in, const int* in_sizes, int n_in,
                              void* d_out, int out_size, void* d_ws, size_t ws_size,
                              hipStream_t stream) {
  const int* tokens = (const int*)d_in[0];
  const float* emb = (const float*)d_in[1];
  const float* w_ih0 = (const float*)d_in[2];
  const float* w_hh0 = (const float*)d_in[3];
  const float* b_ih0 = (const float*)d_in[4];
  const float* b_hh0 = (const float*)d_in[5];
  const float* w_ih1 = (const float*)d_in[6];
  const float* w_hh1 = (const float*)d_in[7];
  const float* b_ih1 = (const float*)d_in[8];
  const float* b_hh1 = (const float*)d_in[9];
  const float* fc_w = (const float*)d_in[10];
  const float* fc_b = (const float*)d_in[11];
  float* out = (float*)d_out;

  char* ws = (char*)d_ws;
  size_t off = 0;
  auto alloc = [&](size_t bytes) -> void* {
    void* p = ws + off;
    off += (bytes + 255) & ~(size_t)255;
    return p;
  };
  _Float16* W0f = (_Float16*)alloc(192L * 10 * 512 * 2);   // w_ih0 frags (K 300->320)
  _Float16* W1f = (_Float16*)alloc(192L * 32 * 512 * 2);   // w_ih1 frags (K=1024)
  _Float16* Wh0f = (_Float16*)alloc(192L * 16 * 512 * 2);  // w_hh0 frags
  _Float16* Wh1f = (_Float16*)alloc(192L * 16 * 512 * 2);  // w_hh1 frags
  _Float16* x0f = (_Float16*)alloc(2048L * 10 * 512 * 2);  // embedded input frags
  _Float16* x1f = (_Float16*)alloc(2048L * 32 * 512 * 2);  // layer-0 output frags
  _Float16* gxb = (_Float16*)alloc(2048L * 192 * 256 * 2); // gx (shared L0/L1)
  char* hz = ws + off;                                     // memset region start
  _Float16* hbuf = (_Float16*)alloc(4L * 32 * 8192 * 2);   // h double-buffer, 2 dirs
  unsigned int* cnt = (unsigned int*)alloc(4096);          // group barrier flags
  const size_t hz_bytes = 4L * 32 * 8192 * 2 + 4096;
  float* lastb = (float*)alloc(512L * 1024 * 4);
  if (off > ws_size) return;  // workspace too small -> visible absmax failure

  pack_b_kernel<<<dim3(192 * 10 * 64 / 256), 256, 0, stream>>>(w_ih0, W0f, 300, 10);
  pack_b_kernel<<<dim3(192 * 32 * 64 / 256), 256, 0, stream>>>(w_ih1, W1f, 1024, 32);
  pack_b_kernel<<<dim3(192 * 16 * 64 / 256), 256, 0, stream>>>(w_hh0, Wh0f, 512, 16);
  pack_b_kernel<<<dim3(192 * 16 * 64 / 256), 256, 0, stream>>>(w_hh1, Wh1f, 512, 16);
  gather_kernel<<<dim3(2048 * 10 * 64 / 256), 256, 0, stream>>>(tokens, emb, x0f);

  gemm_bt_kernel<<<dim3(24, 256), 256, 0, stream>>>(x0f, W0f, b_ih0, gxb, 10);
  hipMemsetAsync(hz, 0, hz_bytes, stream);
  gru_scan_kernel<<<dim3(256), 256, 0, stream>>>(Wh0f, b_hh0, gxb, hbuf, x1f, nullptr, cnt);

  gemm_bt_kernel<<<dim3(24, 256), 256, 0, stream>>>(x1f, W1f, b_ih1, gxb, 32);
  hipMemsetAsync(hz, 0, hz_bytes, stream);
  gru_scan_kernel<<<dim3(256), 256, 0, stream>>>(Wh1f, b_hh1, gxb, hbuf, nullptr, lastb, cnt);

  fc_kernel<<<dim3(512), 64, 0, stream>>>(lastb, fc_w, fc_b, out);
}